// Round 6
// baseline (197.334 us; speedup 1.0000x reference)
//
#include <hip/hip_runtime.h>
#include <math.h>

#define DV 512
#define HD 64
#define NHEADS 8
#define SEQ 1024
#define NBATCH 8
#define MROWS (NBATCH * SEQ)   // 8192

typedef __bf16 bf16;
typedef __bf16 bf16x8 __attribute__((ext_vector_type(8)));
typedef __bf16 bf16x4 __attribute__((ext_vector_type(4)));
typedef float f32x4 __attribute__((ext_vector_type(4)));

__device__ inline void gload_lds16(const void* g, void* l) {
  __builtin_amdgcn_global_load_lds(
      (const __attribute__((address_space(1))) unsigned int*)g,
      (__attribute__((address_space(3))) unsigned int*)l, 16, 0, 0);
}

// ---------------------------------------------------------------------------
// Weight prep: W [512,512] f32 -> W^T bf16.  grid (64,1,4).
// ---------------------------------------------------------------------------
__global__ __launch_bounds__(256) void prep_w(
    const float* __restrict__ W0, const float* __restrict__ W1,
    const float* __restrict__ W2, const float* __restrict__ W3,
    bf16* __restrict__ T0, bf16* __restrict__ T1,
    bf16* __restrict__ T2, bf16* __restrict__ T3)
{
  const int z = blockIdx.z;
  const float* W = z == 0 ? W0 : z == 1 ? W1 : z == 2 ? W2 : W3;
  bf16* WT = z == 0 ? T0 : z == 1 ? T1 : z == 2 ? T2 : T3;
  __shared__ float T[64][65];
  const int t = threadIdx.x;
  const int k0 = (blockIdx.x >> 3) * 64, n0 = (blockIdx.x & 7) * 64;
#pragma unroll
  for (int p = 0; p < 4; ++p) {
    int r = p * 16 + (t >> 4), c = (t & 15) * 4;
    float4 v = *(const float4*)&W[(size_t)(k0 + r) * DV + n0 + c];
    T[r][c] = v.x; T[r][c + 1] = v.y; T[r][c + 2] = v.z; T[r][c + 3] = v.w;
  }
  __syncthreads();
#pragma unroll
  for (int p = 0; p < 2; ++p) {
    int n = p * 32 + (t >> 3), kc = (t & 7) * 8;
    bf16x8 o;
#pragma unroll
    for (int j = 0; j < 8; ++j) o[j] = (bf16)T[kc + j][n];
    *(bf16x8*)&WT[(size_t)(n0 + n) * DV + k0 + kc] = o;
  }
}

// ---------------------------------------------------------------------------
// Mixed-staging dbuf 128x128 GEMM core.  AF/BF: that operand is f32 in global
// and gets cast->bf16 during manual LDS staging (loads issued right after the
// barrier, cvt+ds_write after the MFMA block -> latency hidden by compute).
// bf16 operands use global_load_lds.  LDS granule (row,kq of 8 bf16) at slot
// row*8 + (kq ^ (row&7)); K fixed at 512, BK=64, 8 iters.
// ---------------------------------------------------------------------------
template<bool AF, bool BF>
__device__ __forceinline__ void proj_core(
    const float* Af, const bf16* Ab, const float* Bf, const bf16* Bb,
    bf16* As, bf16* Bs, int m0, int n0, f32x4 (*acc)[4])
{
  const int tid = threadIdx.x;
  const int lane = tid & 63, w = tid >> 6;
  const int wm = w >> 1, wn = w & 1;
  const int cl = lane & 15, qd = lane >> 4;

  size_t offA[4], offB[4];
  int uOff[4], sOff[4];
#pragma unroll
  for (int t = 0; t < 4; ++t) {
    int S = t * 256 + tid;
    int row = S >> 3, kq = (S & 7) ^ (row & 7);
    offA[t] = (size_t)(m0 + row) * DV + kq * 8;
    offB[t] = (size_t)(n0 + row) * DV + kq * 8;
    uOff[t] = (t * 256 + w * 64) * 8;   // wave-uniform base for gload
    sOff[t] = S * 8;                    // per-lane slot for manual write
  }

  float4 ra0[4], ra1[4], rb0[4], rb1[4];

  // prologue: tile 0 -> buffer 0
#pragma unroll
  for (int t = 0; t < 4; ++t) {
    if (AF) {
      ra0[t] = *(const float4*)(Af + offA[t]);
      ra1[t] = *(const float4*)(Af + offA[t] + 4);
      bf16x8 o;
      o[0]=(bf16)ra0[t].x; o[1]=(bf16)ra0[t].y; o[2]=(bf16)ra0[t].z; o[3]=(bf16)ra0[t].w;
      o[4]=(bf16)ra1[t].x; o[5]=(bf16)ra1[t].y; o[6]=(bf16)ra1[t].z; o[7]=(bf16)ra1[t].w;
      *(bf16x8*)(As + sOff[t]) = o;
    } else {
      gload_lds16(Ab + offA[t], As + uOff[t]);
    }
    if (BF) {
      rb0[t] = *(const float4*)(Bf + offB[t]);
      rb1[t] = *(const float4*)(Bf + offB[t] + 4);
      bf16x8 o;
      o[0]=(bf16)rb0[t].x; o[1]=(bf16)rb0[t].y; o[2]=(bf16)rb0[t].z; o[3]=(bf16)rb0[t].w;
      o[4]=(bf16)rb1[t].x; o[5]=(bf16)rb1[t].y; o[6]=(bf16)rb1[t].z; o[7]=(bf16)rb1[t].w;
      *(bf16x8*)(Bs + sOff[t]) = o;
    } else {
      gload_lds16(Bb + offB[t], Bs + uOff[t]);
    }
  }

  for (int it = 0; it < 8; ++it) {
    __syncthreads();                        // publish buf(it)
    const int cur = it & 1;
    const int nb = (cur ^ 1) * 8192;
    const bool has = (it + 1 < 8);
    const size_t k0n = (size_t)(it + 1) * 64;
    if (has) {                              // issue next-tile loads now
#pragma unroll
      for (int t = 0; t < 4; ++t) {
        if (AF) { ra0[t] = *(const float4*)(Af + k0n + offA[t]);
                  ra1[t] = *(const float4*)(Af + k0n + offA[t] + 4); }
        else    gload_lds16(Ab + k0n + offA[t], As + nb + uOff[t]);
        if (BF) { rb0[t] = *(const float4*)(Bf + k0n + offB[t]);
                  rb1[t] = *(const float4*)(Bf + k0n + offB[t] + 4); }
        else    gload_lds16(Bb + k0n + offB[t], Bs + nb + uOff[t]);
      }
    }
    const bf16* A_ = As + cur * 8192;
    const bf16* B_ = Bs + cur * 8192;
#pragma unroll
    for (int cc = 0; cc < 2; ++cc) {
      bf16x8 af[4], bfr[4];
#pragma unroll
      for (int mi = 0; mi < 4; ++mi) {
        int row = wm * 64 + mi * 16 + cl;
        int slot = row * 8 + ((cc * 4 + qd) ^ (row & 7));
        af[mi] = *(const bf16x8*)(A_ + (size_t)slot * 8);
      }
#pragma unroll
      for (int ni = 0; ni < 4; ++ni) {
        int row = wn * 64 + ni * 16 + cl;
        int slot = row * 8 + ((cc * 4 + qd) ^ (row & 7));
        bfr[ni] = *(const bf16x8*)(B_ + (size_t)slot * 8);
      }
#pragma unroll
      for (int mi = 0; mi < 4; ++mi)
#pragma unroll
        for (int ni = 0; ni < 4; ++ni)
          acc[mi][ni] = __builtin_amdgcn_mfma_f32_16x16x32_bf16(
              af[mi], bfr[ni], acc[mi][ni], 0, 0, 0);
    }
    if (has) {                              // cvt + write next tile (manual paths)
#pragma unroll
      for (int t = 0; t < 4; ++t) {
        if (AF) {
          bf16x8 o;
          o[0]=(bf16)ra0[t].x; o[1]=(bf16)ra0[t].y; o[2]=(bf16)ra0[t].z; o[3]=(bf16)ra0[t].w;
          o[4]=(bf16)ra1[t].x; o[5]=(bf16)ra1[t].y; o[6]=(bf16)ra1[t].z; o[7]=(bf16)ra1[t].w;
          *(bf16x8*)(As + nb + sOff[t]) = o;
        }
        if (BF) {
          bf16x8 o;
          o[0]=(bf16)rb0[t].x; o[1]=(bf16)rb0[t].y; o[2]=(bf16)rb0[t].z; o[3]=(bf16)rb0[t].w;
          o[4]=(bf16)rb1[t].x; o[5]=(bf16)rb1[t].y; o[6]=(bf16)rb1[t].z; o[7]=(bf16)rb1[t].w;
          *(bf16x8*)(Bs + nb + sOff[t]) = o;
        }
      }
    }
  }
}

// Batched projection: z=0 Qp=Q@Wq+bq, z=1 Kp=K@Wk+bk (f32 A, bf16 B^T),
// z=2 VpT = WvT @ K^T + bv[row] (bf16 A, f32 B).
__global__ __launch_bounds__(256) void gemm_proj(
    const float* __restrict__ Qf, const float* __restrict__ Kf,
    const bf16* __restrict__ WqT, const bf16* __restrict__ WkT,
    const bf16* __restrict__ WvT,
    const float* __restrict__ bq, const float* __restrict__ bk,
    const float* __restrict__ bv,
    bf16* __restrict__ Qp, bf16* __restrict__ Kp, bf16* __restrict__ VpT)
{
  __shared__ bf16 As[2 * 8192];
  __shared__ bf16 Bs[2 * 8192];
  const int z = blockIdx.z;
  int bx, by, N;
  if (z < 2) { bx = blockIdx.x & 3;  by = blockIdx.x >> 2; N = DV; }
  else       { bx = blockIdx.x & 63; by = blockIdx.x >> 6; N = MROWS; }
  const int m0 = by * 128, n0 = bx * 128;

  f32x4 acc[4][4] = {};
  const float* bias;
  bf16* C;
  if (z == 0) { proj_core<true,  false>(Qf, nullptr, nullptr, WqT, As, Bs, m0, n0, acc); bias = bq; C = Qp; }
  else if (z == 1) { proj_core<true,  false>(Kf, nullptr, nullptr, WkT, As, Bs, m0, n0, acc); bias = bk; C = Kp; }
  else { proj_core<false, true>(nullptr, WvT, Kf, nullptr, As, Bs, m0, n0, acc); bias = bv; C = VpT; }

  const int lane = threadIdx.x & 63, w = threadIdx.x >> 6;
  const int wm = w >> 1, wn = w & 1;
  const int cl = lane & 15, qd = lane >> 4;
  float bcol[4] = {0.f, 0.f, 0.f, 0.f};
  if (z < 2)
#pragma unroll
    for (int ni = 0; ni < 4; ++ni) bcol[ni] = bias[n0 + wn * 64 + ni * 16 + cl];
#pragma unroll
  for (int mi = 0; mi < 4; ++mi)
#pragma unroll
    for (int r = 0; r < 4; ++r) {
      int gm = m0 + wm * 64 + mi * 16 + qd * 4 + r;
      float brow = (z == 2) ? bias[gm] : 0.f;
#pragma unroll
      for (int ni = 0; ni < 4; ++ni) {
        int gn = n0 + wn * 64 + ni * 16 + cl;
        float v = acc[mi][ni][r] + (z == 2 ? brow : bcol[ni]);
        C[(size_t)gm * N + gn] = (bf16)v;
      }
    }
}

// ---------------------------------------------------------------------------
// MFMA flash attention (S^T = K Q^T, O^T = V^T P^T), no-max softmax, dbuf
// single-barrier K/V pipeline.  Epilogue fuses Q-residual, writes bf16.
// ---------------------------------------------------------------------------
__global__ __launch_bounds__(256) void attn_mfma(
    const bf16* __restrict__ Qp, const bf16* __restrict__ Kp,
    const bf16* __restrict__ VpT, bf16* __restrict__ Orb)
{
  __shared__ bf16 Ks[2][64 * 64];
  __shared__ bf16 Vs[2][64 * 64];
  __shared__ bf16 Ps[4][32 * 72];

  const int tid = threadIdx.x, lane = tid & 63, w = tid >> 6;
  const int cl = lane & 15, qd = lane >> 4;
  const int bh = blockIdx.y, b = bh >> 3, h = bh & 7;
  const int q0w = blockIdx.x * 128 + w * 32;

  const float SCL = 0.18033688011112042f;   // log2(e)/8 folded into Q
  bf16x8 qa[2][2];
#pragma unroll
  for (int qt = 0; qt < 2; ++qt)
#pragma unroll
    for (int ch = 0; ch < 2; ++ch) {
      bf16x8 v = *(const bf16x8*)(Qp + ((size_t)b * SEQ + q0w + qt * 16 + cl) * DV
                                  + h * HD + ch * 32 + qd * 8);
#pragma unroll
      for (int j = 0; j < 8; ++j) v[j] = (bf16)((float)v[j] * SCL);
      qa[qt][ch] = v;
    }

  f32x4 o[4][2] = {};
  float lrun[2] = {0.f, 0.f};

  const bf16* Kbase = Kp + (size_t)b * SEQ * DV + h * HD;
  const bf16* Vbase = VpT + (size_t)h * HD * MROWS + (size_t)b * SEQ;
  bf16* Pw = &Ps[w][0];

  const int Sa = tid, Sb = 256 + tid;
  const int kRowA = Sa >> 3, kDgA = (Sa & 7) ^ (kRowA & 7);
  const int kRowB = Sb >> 3, kDgB = (Sb & 7) ^ (kRowB & 7);
  const size_t kOffA = (size_t)kRowA * DV + kDgA * 8;
  const size_t kOffB = (size_t)kRowB * DV + kDgB * 8;
  const size_t vOffA = (size_t)kRowA * MROWS + kDgA * 8;
  const size_t vOffB = (size_t)kRowB * MROWS + kDgB * 8;

  gload_lds16(Kbase + kOffA, &Ks[0][(size_t)(w * 64) * 8]);
  gload_lds16(Kbase + kOffB, &Ks[0][(size_t)(256 + w * 64) * 8]);
  gload_lds16(Vbase + vOffA, &Vs[0][(size_t)(w * 64) * 8]);
  gload_lds16(Vbase + vOffB, &Vs[0][(size_t)(256 + w * 64) * 8]);

  for (int it = 0; it < SEQ / 64; ++it) {
    __syncthreads();
    const int cur = it & 1;
    if (it + 1 < SEQ / 64) {
      const size_t kt = (size_t)(it + 1) * 64;
      gload_lds16(Kbase + kt * DV + kOffA, &Ks[cur ^ 1][(size_t)(w * 64) * 8]);
      gload_lds16(Kbase + kt * DV + kOffB, &Ks[cur ^ 1][(size_t)(256 + w * 64) * 8]);
      gload_lds16(Vbase + kt + vOffA, &Vs[cur ^ 1][(size_t)(w * 64) * 8]);
      gload_lds16(Vbase + kt + vOffB, &Vs[cur ^ 1][(size_t)(256 + w * 64) * 8]);
    }
    const bf16* K_ = &Ks[cur][0];
    const bf16* V_ = &Vs[cur][0];

    f32x4 sc[4][2] = {};
#pragma unroll
    for (int ch = 0; ch < 2; ++ch) {
      bf16x8 kf[4];
#pragma unroll
      for (int kt4 = 0; kt4 < 4; ++kt4) {
        int key = kt4 * 16 + cl;
        int slot = key * 8 + ((ch * 4 + qd) ^ (key & 7));
        kf[kt4] = *(const bf16x8*)(K_ + (size_t)slot * 8);
      }
#pragma unroll
      for (int kt4 = 0; kt4 < 4; ++kt4)
#pragma unroll
        for (int qt = 0; qt < 2; ++qt)
          sc[kt4][qt] = __builtin_amdgcn_mfma_f32_16x16x32_bf16(
              kf[kt4], qa[qt][ch], sc[kt4][qt], 0, 0, 0);
    }

#pragma unroll
    for (int qt = 0; qt < 2; ++qt) {
      float sum = 0.f;
#pragma unroll
      for (int kt4 = 0; kt4 < 4; ++kt4) {
        float p0 = __builtin_amdgcn_exp2f(sc[kt4][qt][0]);
        float p1 = __builtin_amdgcn_exp2f(sc[kt4][qt][1]);
        float p2 = __builtin_amdgcn_exp2f(sc[kt4][qt][2]);
        float p3 = __builtin_amdgcn_exp2f(sc[kt4][qt][3]);
        sum += (p0 + p1) + (p2 + p3);
        bf16x4 pk;
        pk[0] = (bf16)p0; pk[1] = (bf16)p1; pk[2] = (bf16)p2; pk[3] = (bf16)p3;
        *(bf16x4*)(Pw + (size_t)(qt * 16 + cl) * 72 + kt4 * 16 + qd * 4) = pk;
      }
      sum += __shfl_xor(sum, 16);
      sum += __shfl_xor(sum, 32);
      lrun[qt] += sum;
    }

#pragma unroll
    for (int kc = 0; kc < 2; ++kc) {
      bf16x8 pb[2];
#pragma unroll
      for (int qt = 0; qt < 2; ++qt)
        pb[qt] = *(const bf16x8*)(Pw + (size_t)(qt * 16 + cl) * 72 + kc * 32 + qd * 8);
#pragma unroll
      for (int dt = 0; dt < 4; ++dt) {
        int d = dt * 16 + cl;
        int slot = d * 8 + ((kc * 4 + qd) ^ (d & 7));
        bf16x8 vf = *(const bf16x8*)(V_ + (size_t)slot * 8);
#pragma unroll
        for (int qt = 0; qt < 2; ++qt)
          o[dt][qt] = __builtin_amdgcn_mfma_f32_16x16x32_bf16(
              vf, pb[qt], o[dt][qt], 0, 0, 0);
      }
    }
  }

#pragma unroll
  for (int qt = 0; qt < 2; ++qt) {
    float inv = 1.f / lrun[qt];
    size_t rowoff = ((size_t)b * SEQ + q0w + qt * 16 + cl) * DV + h * HD;
#pragma unroll
    for (int dt = 0; dt < 4; ++dt) {
      bf16x4 rv = *(const bf16x4*)(Qp + rowoff + dt * 16 + qd * 4);
      bf16x4 st;
      st[0] = (bf16)(o[dt][qt][0] * inv + (float)rv[0]);
      st[1] = (bf16)(o[dt][qt][1] * inv + (float)rv[1]);
      st[2] = (bf16)(o[dt][qt][2] * inv + (float)rv[2]);
      st[3] = (bf16)(o[dt][qt][3] * inv + (float)rv[3]);
      *(bf16x4*)(Orb + rowoff + dt * 16 + qd * 4) = st;
    }
  }
}

// ---------------------------------------------------------------------------
// Fused tail: per block of 32 rows,
//   Xb = LN0(Orb)           (prologue, normalized rows stay LDS-resident)
//   Y  = Xb + relu(Xb@Wo+bo)  computed TRANSPOSED (C^T = WoT(A) @ Xb^T(B)),
//        so lane owns fixed q-row (col=cl) and 4 consecutive features per reg
//   out = LN1(Y)             (2 shuffles + small LDS combine, full row local)
// LDS: Bsm 32KB resident normalized rows + As 32KB A-tile (reused as scratch).
// ---------------------------------------------------------------------------
__global__ __launch_bounds__(256) void gemm_fused(
    const bf16* __restrict__ Orb, const bf16* __restrict__ WoT,
    const float* __restrict__ bo,
    const float* __restrict__ g0, const float* __restrict__ b0,
    const float* __restrict__ g1, const float* __restrict__ b1,
    float* __restrict__ out)
{
  __shared__ bf16 Bsm[32 * 512];       // slot = q*64 + (g ^ (q&7)), g = col/8
  __shared__ bf16 As[2048 * 8];        // WoT tile 512f x 32k; scratch after loop
  const int tid = threadIdx.x, lane = tid & 63, w = tid >> 6;
  const int cl = lane & 15, qd = lane >> 4;
  const int m0 = blockIdx.x * 32;

  // ---- LN0 prologue: thread owns row q=tid>>3, cols (tid&7)*64..+63 ----
  {
    const int q = tid >> 3, c0 = (tid & 7) * 64;
    const bf16* src = Orb + (size_t)(m0 + q) * DV + c0;
    float x[64];
    float s = 0.f, s2 = 0.f;
#pragma unroll
    for (int j = 0; j < 8; ++j) {
      bf16x8 xv = *(const bf16x8*)(src + j * 8);
#pragma unroll
      for (int e = 0; e < 8; ++e) {
        float f = (float)xv[e];
        x[j * 8 + e] = f; s += f; s2 += f * f;
      }
    }
    s  += __shfl_xor(s, 1);  s  += __shfl_xor(s, 2);  s  += __shfl_xor(s, 4);
    s2 += __shfl_xor(s2, 1); s2 += __shfl_xor(s2, 2); s2 += __shfl_xor(s2, 4);
    float mu = s * (1.f / DV);
    float inv = rsqrtf(s2 * (1.f / DV) - mu * mu + 1e-5f);
#pragma unroll
    for (int j = 0; j < 8; ++j) {
      float4 ga = *(const float4*)(g0 + c0 + j * 8);
      float4 gb = *(const float4*)(g0 + c0 + j * 8 + 4);
      float4 ba = *(const float4*)(b0 + c0 + j * 8);
      float4 bb = *(const float4*)(b0 + c0 + j * 8 + 4);
      bf16x8 o;
      o[0] = (bf16)((x[j*8+0] - mu) * inv * ga.x + ba.x);
      o[1] = (bf16)((x[j*8+1] - mu) * inv * ga.y + ba.y);
      o[2] = (bf16)((x[j*8+2] - mu) * inv * ga.z + ba.z);
      o[3] = (bf16)((x[j*8+3] - mu) * inv * ga.w + ba.w);
      o[4] = (bf16)((x[j*8+4] - mu) * inv * gb.x + bb.x);
      o[5] = (bf16)((x[j*8+5] - mu) * inv * gb.y + bb.y);
      o[6] = (bf16)((x[j*8+6] - mu) * inv * gb.z + bb.z);
      o[7] = (bf16)((x[j*8+7] - mu) * inv * gb.w + bb.w);
      int g = (tid & 7) * 8 + j;
      int slot = q * 64 + (g ^ (q & 7));
      *(bf16x8*)(Bsm + (size_t)slot * 8) = o;
    }
  }
  __syncthreads();

  // ---- K-loop: wave owns feature-tiles w*8..w*8+7 (128 features) ----
  size_t offA[8];
  int uOff[8];
#pragma unroll
  for (int t = 0; t < 8; ++t) {
    int S = t * 256 + tid;
    int frow = S >> 2, kq = (S & 3) ^ ((frow >> 1) & 3);
    offA[t] = (size_t)frow * DV + kq * 8;
    uOff[t] = (t * 256 + w * 64) * 8;
  }

  f32x4 acc[8][2] = {};
  for (int it = 0; it < 16; ++it) {
    __syncthreads();                       // As safe to overwrite
#pragma unroll
    for (int t = 0; t < 8; ++t)
      gload_lds16(WoT + (size_t)it * 32 + offA[t], As + uOff[t]);
    __syncthreads();                       // drain, publish

    bf16x8 bfr[2];
#pragma unroll
    for (int nt = 0; nt < 2; ++nt) {
      int q = nt * 16 + cl;
      int slot = q * 64 + ((it * 4 + qd) ^ (q & 7));
      bfr[nt] = *(const bf16x8*)(Bsm + (size_t)slot * 8);
    }
#pragma unroll
    for (int mt = 0; mt < 8; ++mt) {
      int frow = (w * 8 + mt) * 16 + cl;
      int slot = frow * 4 + (qd ^ ((frow >> 1) & 3));
      bf16x8 af = *(const bf16x8*)(As + (size_t)slot * 8);
#pragma unroll
      for (int nt = 0; nt < 2; ++nt)
        acc[mt][nt] = __builtin_amdgcn_mfma_f32_16x16x32_bf16(
            af, bfr[nt], acc[mt][nt], 0, 0, 0);
    }
  }

  // ---- epilogue: Y = res + relu(acc + bo), then LN1 over full rows ----
  __syncthreads();                          // As now reusable as scratch
  float* red = (float*)As;                  // [32 q][4 w][2]
  float y[8][2][4];
  float sy[2], sy2[2];
#pragma unroll
  for (int nt = 0; nt < 2; ++nt) {
    sy[nt] = 0.f; sy2[nt] = 0.f;
    const int q = nt * 16 + cl;
#pragma unroll
    for (int mt = 0; mt < 8; ++mt) {
      const int f0 = (w * 8 + mt) * 16 + qd * 4;
      float4 bov = *(const float4*)(bo + f0);
      int g = f0 >> 3;
      int slot = q * 64 + (g ^ (q & 7));
      bf16x4 rv = *(const bf16x4*)(Bsm + (size_t)slot * 8 + (qd & 1) * 4);
      const float* bp = (const float*)&bov;
#pragma unroll
      for (int r = 0; r < 4; ++r) {
        float v = fmaxf(acc[mt][nt][r] + bp[r], 0.f) + (float)rv[r];
        y[mt][nt][r] = v;
        sy[nt] += v; sy2[nt] += v * v;
      }
    }
    sy[nt]  += __shfl_xor(sy[nt], 16);  sy[nt]  += __shfl_xor(sy[nt], 32);
    sy2[nt] += __shfl_xor(sy2[nt], 16); sy2[nt] += __shfl_xor(sy2[nt], 32);
  }
  if (qd == 0) {
#pragma unroll
    for (int nt = 0; nt < 2; ++nt) {
      int q = nt * 16 + cl;
      red[(q * 4 + w) * 2 + 0] = sy[nt];
      red[(q * 4 + w) * 2 + 1] = sy2[nt];
    }
  }
  __syncthreads();
#pragma unroll
  for (int nt = 0; nt < 2; ++nt) {
    const int q = nt * 16 + cl;
    float s = 0.f, s2 = 0.f;
#pragma unroll
    for (int ww = 0; ww < 4; ++ww) {
      s  += red[(q * 4 + ww) * 2 + 0];
      s2 += red[(q * 4 + ww) * 2 + 1];
    }
    float mu1 = s * (1.f / DV);
    float inv1 = rsqrtf(s2 * (1.f / DV) - mu1 * mu1 + 1e-5f);
    size_t rowoff = (size_t)(m0 + q) * DV;
#pragma unroll
    for (int mt = 0; mt < 8; ++mt) {
      const int f0 = (w * 8 + mt) * 16 + qd * 4;
      float4 gv = *(const float4*)(g1 + f0);
      float4 bv = *(const float4*)(b1 + f0);
      float4 ov;
      ov.x = (y[mt][nt][0] - mu1) * inv1 * gv.x + bv.x;
      ov.y = (y[mt][nt][1] - mu1) * inv1 * gv.y + bv.y;
      ov.z = (y[mt][nt][2] - mu1) * inv1 * gv.z + bv.z;
      ov.w = (y[mt][nt][3] - mu1) * inv1 * gv.w + bv.w;
      *(float4*)(out + rowoff + f0) = ov;
    }
  }
}

extern "C" void kernel_launch(void* const* d_in, const int* in_sizes, int n_in,
                              void* d_out, int out_size, void* d_ws, size_t ws_size,
                              hipStream_t stream)
{
  const float* Q  = (const float*)d_in[0];
  const float* Kf = (const float*)d_in[1];
  const float* Wq = (const float*)d_in[2];
  const float* bq = (const float*)d_in[3];
  const float* Wk = (const float*)d_in[4];
  const float* bk = (const float*)d_in[5];
  const float* Wv = (const float*)d_in[6];
  const float* bv = (const float*)d_in[7];
  const float* Wo = (const float*)d_in[8];
  const float* bo = (const float*)d_in[9];
  const float* g0 = (const float*)d_in[10];
  const float* b0 = (const float*)d_in[11];
  const float* g1 = (const float*)d_in[12];
  const float* b1 = (const float*)d_in[13];
  float* out = (float*)d_out;

  const size_t MB = 1ull << 20;
  char* W = (char*)d_ws;
  bf16* Orb = (bf16*)(W + 0);                    // 8 MB
  bf16* Qp  = (bf16*)(W + 8 * MB);
  bf16* Kp  = (bf16*)(W + 16 * MB);
  bf16* VpT = (bf16*)(W + 24 * MB);              // [512][8192]
  bf16* WqT = (bf16*)(W + 32 * MB);
  bf16* WkT = (bf16*)(W + 32 * MB + 512 * 1024);
  bf16* WvT = (bf16*)(W + 33 * MB);
  bf16* WoT = (bf16*)(W + 33 * MB + 512 * 1024);

  dim3 blk(256);
  prep_w<<<dim3(64, 1, 4), blk, 0, stream>>>(Wq, Wk, Wv, Wo, WqT, WkT, WvT, WoT);
  gemm_proj<<<dim3(256, 1, 3), blk, 0, stream>>>(
      Q, Kf, WqT, WkT, WvT, bq, bk, bv, Qp, Kp, VpT);
  attn_mfma<<<dim3(SEQ / 128, NBATCH * NHEADS), blk, 0, stream>>>(Qp, Kp, VpT, Orb);
  gemm_fused<<<dim3(MROWS / 32), blk, 0, stream>>>(
      Orb, WoT, bo, g0, b0, g1, b1, out);
}

// Round 7
// 185.236 us; speedup vs baseline: 1.0653x; 1.0653x over previous
//
#include <hip/hip_runtime.h>
#include <math.h>

#define DV 512
#define HD 64
#define NHEADS 8
#define SEQ 1024
#define NBATCH 8
#define MROWS (NBATCH * SEQ)   // 8192

typedef __bf16 bf16;
typedef __bf16 bf16x8 __attribute__((ext_vector_type(8)));
typedef __bf16 bf16x4 __attribute__((ext_vector_type(4)));
typedef float f32x4 __attribute__((ext_vector_type(4)));

__device__ inline void gload_lds16(const void* g, void* l) {
  __builtin_amdgcn_global_load_lds(
      (const __attribute__((address_space(1))) unsigned int*)g,
      (__attribute__((address_space(3))) unsigned int*)l, 16, 0, 0);
}

// ---------------------------------------------------------------------------
// Weight prep: W [512,512] f32 -> W^T bf16.  grid (64,1,4).
// ---------------------------------------------------------------------------
__global__ __launch_bounds__(256) void prep_w(
    const float* __restrict__ W0, const float* __restrict__ W1,
    const float* __restrict__ W2, const float* __restrict__ W3,
    bf16* __restrict__ T0, bf16* __restrict__ T1,
    bf16* __restrict__ T2, bf16* __restrict__ T3)
{
  const int z = blockIdx.z;
  const float* W = z == 0 ? W0 : z == 1 ? W1 : z == 2 ? W2 : W3;
  bf16* WT = z == 0 ? T0 : z == 1 ? T1 : z == 2 ? T2 : T3;
  __shared__ float T[64][65];
  const int t = threadIdx.x;
  const int k0 = (blockIdx.x >> 3) * 64, n0 = (blockIdx.x & 7) * 64;
#pragma unroll
  for (int p = 0; p < 4; ++p) {
    int r = p * 16 + (t >> 4), c = (t & 15) * 4;
    float4 v = *(const float4*)&W[(size_t)(k0 + r) * DV + n0 + c];
    T[r][c] = v.x; T[r][c + 1] = v.y; T[r][c + 2] = v.z; T[r][c + 3] = v.w;
  }
  __syncthreads();
#pragma unroll
  for (int p = 0; p < 2; ++p) {
    int n = p * 32 + (t >> 3), kc = (t & 7) * 8;
    bf16x8 o;
#pragma unroll
    for (int j = 0; j < 8; ++j) o[j] = (bf16)T[kc + j][n];
    *(bf16x8*)&WT[(size_t)(n0 + n) * DV + k0 + kc] = o;
  }
}

// ---------------------------------------------------------------------------
// Mixed-staging dbuf 128x128 GEMM core (f32 operand cast during staging).
// ---------------------------------------------------------------------------
template<bool AF, bool BF>
__device__ __forceinline__ void proj_core(
    const float* Af, const bf16* Ab, const float* Bf, const bf16* Bb,
    bf16* As, bf16* Bs, int m0, int n0, f32x4 (*acc)[4])
{
  const int tid = threadIdx.x;
  const int lane = tid & 63, w = tid >> 6;
  const int wm = w >> 1, wn = w & 1;
  const int cl = lane & 15, qd = lane >> 4;

  size_t offA[4], offB[4];
  int uOff[4], sOff[4];
#pragma unroll
  for (int t = 0; t < 4; ++t) {
    int S = t * 256 + tid;
    int row = S >> 3, kq = (S & 7) ^ (row & 7);
    offA[t] = (size_t)(m0 + row) * DV + kq * 8;
    offB[t] = (size_t)(n0 + row) * DV + kq * 8;
    uOff[t] = (t * 256 + w * 64) * 8;   // wave-uniform base for gload
    sOff[t] = S * 8;                    // per-lane slot for manual write
  }

  float4 ra0[4], ra1[4], rb0[4], rb1[4];

#pragma unroll
  for (int t = 0; t < 4; ++t) {
    if (AF) {
      ra0[t] = *(const float4*)(Af + offA[t]);
      ra1[t] = *(const float4*)(Af + offA[t] + 4);
      bf16x8 o;
      o[0]=(bf16)ra0[t].x; o[1]=(bf16)ra0[t].y; o[2]=(bf16)ra0[t].z; o[3]=(bf16)ra0[t].w;
      o[4]=(bf16)ra1[t].x; o[5]=(bf16)ra1[t].y; o[6]=(bf16)ra1[t].z; o[7]=(bf16)ra1[t].w;
      *(bf16x8*)(As + sOff[t]) = o;
    } else {
      gload_lds16(Ab + offA[t], As + uOff[t]);
    }
    if (BF) {
      rb0[t] = *(const float4*)(Bf + offB[t]);
      rb1[t] = *(const float4*)(Bf + offB[t] + 4);
      bf16x8 o;
      o[0]=(bf16)rb0[t].x; o[1]=(bf16)rb0[t].y; o[2]=(bf16)rb0[t].z; o[3]=(bf16)rb0[t].w;
      o[4]=(bf16)rb1[t].x; o[5]=(bf16)rb1[t].y; o[6]=(bf16)rb1[t].z; o[7]=(bf16)rb1[t].w;
      *(bf16x8*)(Bs + sOff[t]) = o;
    } else {
      gload_lds16(Bb + offB[t], Bs + uOff[t]);
    }
  }

  for (int it = 0; it < 8; ++it) {
    __syncthreads();                        // publish buf(it)
    const int cur = it & 1;
    const int nb = (cur ^ 1) * 8192;
    const bool has = (it + 1 < 8);
    const size_t k0n = (size_t)(it + 1) * 64;
    if (has) {
#pragma unroll
      for (int t = 0; t < 4; ++t) {
        if (AF) { ra0[t] = *(const float4*)(Af + k0n + offA[t]);
                  ra1[t] = *(const float4*)(Af + k0n + offA[t] + 4); }
        else    gload_lds16(Ab + k0n + offA[t], As + nb + uOff[t]);
        if (BF) { rb0[t] = *(const float4*)(Bf + k0n + offB[t]);
                  rb1[t] = *(const float4*)(Bf + k0n + offB[t] + 4); }
        else    gload_lds16(Bb + k0n + offB[t], Bs + nb + uOff[t]);
      }
    }
    const bf16* A_ = As + cur * 8192;
    const bf16* B_ = Bs + cur * 8192;
#pragma unroll
    for (int cc = 0; cc < 2; ++cc) {
      bf16x8 af[4], bfr[4];
#pragma unroll
      for (int mi = 0; mi < 4; ++mi) {
        int row = wm * 64 + mi * 16 + cl;
        int slot = row * 8 + ((cc * 4 + qd) ^ (row & 7));
        af[mi] = *(const bf16x8*)(A_ + (size_t)slot * 8);
      }
#pragma unroll
      for (int ni = 0; ni < 4; ++ni) {
        int row = wn * 64 + ni * 16 + cl;
        int slot = row * 8 + ((cc * 4 + qd) ^ (row & 7));
        bfr[ni] = *(const bf16x8*)(B_ + (size_t)slot * 8);
      }
#pragma unroll
      for (int mi = 0; mi < 4; ++mi)
#pragma unroll
        for (int ni = 0; ni < 4; ++ni)
          acc[mi][ni] = __builtin_amdgcn_mfma_f32_16x16x32_bf16(
              af[mi], bfr[ni], acc[mi][ni], 0, 0, 0);
    }
    if (has) {
#pragma unroll
      for (int t = 0; t < 4; ++t) {
        if (AF) {
          bf16x8 o;
          o[0]=(bf16)ra0[t].x; o[1]=(bf16)ra0[t].y; o[2]=(bf16)ra0[t].z; o[3]=(bf16)ra0[t].w;
          o[4]=(bf16)ra1[t].x; o[5]=(bf16)ra1[t].y; o[6]=(bf16)ra1[t].z; o[7]=(bf16)ra1[t].w;
          *(bf16x8*)(As + nb + sOff[t]) = o;
        }
        if (BF) {
          bf16x8 o;
          o[0]=(bf16)rb0[t].x; o[1]=(bf16)rb0[t].y; o[2]=(bf16)rb0[t].z; o[3]=(bf16)rb0[t].w;
          o[4]=(bf16)rb1[t].x; o[5]=(bf16)rb1[t].y; o[6]=(bf16)rb1[t].z; o[7]=(bf16)rb1[t].w;
          *(bf16x8*)(Bs + nb + sOff[t]) = o;
        }
      }
    }
  }
}

// Batched projection with XCD-local block mapping: blocks sharing the f32
// operand's rows are 64 apart in blockIdx.x (64 % 8 == 0 -> same XCD -> the
// Q/K f32 rows are fetched once per XCD and stay L2-resident).
__global__ __launch_bounds__(256) void gemm_proj(
    const float* __restrict__ Qf, const float* __restrict__ Kf,
    const bf16* __restrict__ WqT, const bf16* __restrict__ WkT,
    const bf16* __restrict__ WvT,
    const float* __restrict__ bq, const float* __restrict__ bk,
    const float* __restrict__ bv,
    bf16* __restrict__ Qp, bf16* __restrict__ Kp, bf16* __restrict__ VpT)
{
  __shared__ bf16 As[2 * 8192];
  __shared__ bf16 Bs[2 * 8192];
  const int z = blockIdx.z;
  int bx, by, N;
  if (z < 2) { by = blockIdx.x & 63; bx = blockIdx.x >> 6; N = DV; }     // A=f32
  else       { bx = blockIdx.x & 63; by = blockIdx.x >> 6; N = MROWS; }  // B=f32
  const int m0 = by * 128, n0 = bx * 128;

  f32x4 acc[4][4] = {};
  const float* bias;
  bf16* C;
  if (z == 0) { proj_core<true,  false>(Qf, nullptr, nullptr, WqT, As, Bs, m0, n0, acc); bias = bq; C = Qp; }
  else if (z == 1) { proj_core<true,  false>(Kf, nullptr, nullptr, WkT, As, Bs, m0, n0, acc); bias = bk; C = Kp; }
  else { proj_core<false, true>(nullptr, WvT, Kf, nullptr, As, Bs, m0, n0, acc); bias = bv; C = VpT; }

  const int lane = threadIdx.x & 63, w = threadIdx.x >> 6;
  const int wm = w >> 1, wn = w & 1;
  const int cl = lane & 15, qd = lane >> 4;
  float bcol[4] = {0.f, 0.f, 0.f, 0.f};
  if (z < 2)
#pragma unroll
    for (int ni = 0; ni < 4; ++ni) bcol[ni] = bias[n0 + wn * 64 + ni * 16 + cl];
#pragma unroll
  for (int mi = 0; mi < 4; ++mi)
#pragma unroll
    for (int r = 0; r < 4; ++r) {
      int gm = m0 + wm * 64 + mi * 16 + qd * 4 + r;
      float brow = (z == 2) ? bias[gm] : 0.f;
#pragma unroll
      for (int ni = 0; ni < 4; ++ni) {
        int gn = n0 + wn * 64 + ni * 16 + cl;
        float v = acc[mi][ni][r] + (z == 2 ? brow : bcol[ni]);
        C[(size_t)gm * N + gn] = (bf16)v;
      }
    }
}

// ---------------------------------------------------------------------------
// MFMA flash attention (S^T = K Q^T, O^T = V^T P^T), no-max softmax, dbuf
// single-barrier K/V pipeline.  Grid (64 bh, 8 qtile): same-(b,h) blocks are
// 64 apart -> same XCD -> that head's K/V stays L2-resident.
// ---------------------------------------------------------------------------
__global__ __launch_bounds__(256) void attn_mfma(
    const bf16* __restrict__ Qp, const bf16* __restrict__ Kp,
    const bf16* __restrict__ VpT, bf16* __restrict__ Orb)
{
  __shared__ bf16 Ks[2][64 * 64];
  __shared__ bf16 Vs[2][64 * 64];
  __shared__ bf16 Ps[4][32 * 72];

  const int tid = threadIdx.x, lane = tid & 63, w = tid >> 6;
  const int cl = lane & 15, qd = lane >> 4;
  const int bh = blockIdx.x, b = bh >> 3, h = bh & 7;
  const int q0w = blockIdx.y * 128 + w * 32;

  const float SCL = 0.18033688011112042f;   // log2(e)/8 folded into Q
  bf16x8 qa[2][2];
#pragma unroll
  for (int qt = 0; qt < 2; ++qt)
#pragma unroll
    for (int ch = 0; ch < 2; ++ch) {
      bf16x8 v = *(const bf16x8*)(Qp + ((size_t)b * SEQ + q0w + qt * 16 + cl) * DV
                                  + h * HD + ch * 32 + qd * 8);
#pragma unroll
      for (int j = 0; j < 8; ++j) v[j] = (bf16)((float)v[j] * SCL);
      qa[qt][ch] = v;
    }

  f32x4 o[4][2] = {};
  float lrun[2] = {0.f, 0.f};

  const bf16* Kbase = Kp + (size_t)b * SEQ * DV + h * HD;
  const bf16* Vbase = VpT + (size_t)h * HD * MROWS + (size_t)b * SEQ;
  bf16* Pw = &Ps[w][0];

  const int Sa = tid, Sb = 256 + tid;
  const int kRowA = Sa >> 3, kDgA = (Sa & 7) ^ (kRowA & 7);
  const int kRowB = Sb >> 3, kDgB = (Sb & 7) ^ (kRowB & 7);
  const size_t kOffA = (size_t)kRowA * DV + kDgA * 8;
  const size_t kOffB = (size_t)kRowB * DV + kDgB * 8;
  const size_t vOffA = (size_t)kRowA * MROWS + kDgA * 8;
  const size_t vOffB = (size_t)kRowB * MROWS + kDgB * 8;

  gload_lds16(Kbase + kOffA, &Ks[0][(size_t)(w * 64) * 8]);
  gload_lds16(Kbase + kOffB, &Ks[0][(size_t)(256 + w * 64) * 8]);
  gload_lds16(Vbase + vOffA, &Vs[0][(size_t)(w * 64) * 8]);
  gload_lds16(Vbase + vOffB, &Vs[0][(size_t)(256 + w * 64) * 8]);

  for (int it = 0; it < SEQ / 64; ++it) {
    __syncthreads();
    const int cur = it & 1;
    if (it + 1 < SEQ / 64) {
      const size_t kt = (size_t)(it + 1) * 64;
      gload_lds16(Kbase + kt * DV + kOffA, &Ks[cur ^ 1][(size_t)(w * 64) * 8]);
      gload_lds16(Kbase + kt * DV + kOffB, &Ks[cur ^ 1][(size_t)(256 + w * 64) * 8]);
      gload_lds16(Vbase + kt + vOffA, &Vs[cur ^ 1][(size_t)(w * 64) * 8]);
      gload_lds16(Vbase + kt + vOffB, &Vs[cur ^ 1][(size_t)(256 + w * 64) * 8]);
    }
    const bf16* K_ = &Ks[cur][0];
    const bf16* V_ = &Vs[cur][0];

    f32x4 sc[4][2] = {};
#pragma unroll
    for (int ch = 0; ch < 2; ++ch) {
      bf16x8 kf[4];
#pragma unroll
      for (int kt4 = 0; kt4 < 4; ++kt4) {
        int key = kt4 * 16 + cl;
        int slot = key * 8 + ((ch * 4 + qd) ^ (key & 7));
        kf[kt4] = *(const bf16x8*)(K_ + (size_t)slot * 8);
      }
#pragma unroll
      for (int kt4 = 0; kt4 < 4; ++kt4)
#pragma unroll
        for (int qt = 0; qt < 2; ++qt)
          sc[kt4][qt] = __builtin_amdgcn_mfma_f32_16x16x32_bf16(
              kf[kt4], qa[qt][ch], sc[kt4][qt], 0, 0, 0);
    }

#pragma unroll
    for (int qt = 0; qt < 2; ++qt) {
      float sum = 0.f;
#pragma unroll
      for (int kt4 = 0; kt4 < 4; ++kt4) {
        float p0 = __builtin_amdgcn_exp2f(sc[kt4][qt][0]);
        float p1 = __builtin_amdgcn_exp2f(sc[kt4][qt][1]);
        float p2 = __builtin_amdgcn_exp2f(sc[kt4][qt][2]);
        float p3 = __builtin_amdgcn_exp2f(sc[kt4][qt][3]);
        sum += (p0 + p1) + (p2 + p3);
        bf16x4 pk;
        pk[0] = (bf16)p0; pk[1] = (bf16)p1; pk[2] = (bf16)p2; pk[3] = (bf16)p3;
        *(bf16x4*)(Pw + (size_t)(qt * 16 + cl) * 72 + kt4 * 16 + qd * 4) = pk;
      }
      sum += __shfl_xor(sum, 16);
      sum += __shfl_xor(sum, 32);
      lrun[qt] += sum;
    }

#pragma unroll
    for (int kc = 0; kc < 2; ++kc) {
      bf16x8 pb[2];
#pragma unroll
      for (int qt = 0; qt < 2; ++qt)
        pb[qt] = *(const bf16x8*)(Pw + (size_t)(qt * 16 + cl) * 72 + kc * 32 + qd * 8);
#pragma unroll
      for (int dt = 0; dt < 4; ++dt) {
        int d = dt * 16 + cl;
        int slot = d * 8 + ((kc * 4 + qd) ^ (d & 7));
        bf16x8 vf = *(const bf16x8*)(V_ + (size_t)slot * 8);
#pragma unroll
        for (int qt = 0; qt < 2; ++qt)
          o[dt][qt] = __builtin_amdgcn_mfma_f32_16x16x32_bf16(
              vf, pb[qt], o[dt][qt], 0, 0, 0);
      }
    }
  }

#pragma unroll
  for (int qt = 0; qt < 2; ++qt) {
    float inv = 1.f / lrun[qt];
    size_t rowoff = ((size_t)b * SEQ + q0w + qt * 16 + cl) * DV + h * HD;
#pragma unroll
    for (int dt = 0; dt < 4; ++dt) {
      bf16x4 rv = *(const bf16x4*)(Qp + rowoff + dt * 16 + qd * 4);
      bf16x4 st;
      st[0] = (bf16)(o[dt][qt][0] * inv + (float)rv[0]);
      st[1] = (bf16)(o[dt][qt][1] * inv + (float)rv[1]);
      st[2] = (bf16)(o[dt][qt][2] * inv + (float)rv[2]);
      st[3] = (bf16)(o[dt][qt][3] * inv + (float)rv[3]);
      *(bf16x4*)(Orb + rowoff + dt * 16 + qd * 4) = st;
    }
  }
}

// ---------------------------------------------------------------------------
// Fused tail: LN0 -> transposed output GEMM -> +res/relu -> LN1 -> out.
// WoT tile double-buffered (1 block/CU, LDS is free), single barrier/K-iter;
// tile-0 loads issued before the LN0 work so the LN0 barrier drains them.
// ---------------------------------------------------------------------------
__global__ __launch_bounds__(256) void gemm_fused(
    const bf16* __restrict__ Orb, const bf16* __restrict__ WoT,
    const float* __restrict__ bo,
    const float* __restrict__ g0, const float* __restrict__ b0,
    const float* __restrict__ g1, const float* __restrict__ b1,
    float* __restrict__ out)
{
  __shared__ bf16 Bsm[32 * 512];       // slot = q*64 + (g ^ (q&7)), g = col/8
  __shared__ bf16 As[2][2048 * 8];     // WoT tile 512f x 32k, double-buffered
  const int tid = threadIdx.x, lane = tid & 63, w = tid >> 6;
  const int cl = lane & 15, qd = lane >> 4;
  const int m0 = blockIdx.x * 32;

  size_t offA[8];
  int uOff[8];
#pragma unroll
  for (int t = 0; t < 8; ++t) {
    int S = t * 256 + tid;
    int frow = S >> 2, kq = (S & 3) ^ ((frow >> 1) & 3);
    offA[t] = (size_t)frow * DV + kq * 8;
    uOff[t] = (t * 256 + w * 64) * 8;
  }

  // issue WoT tile-0 loads first (drained by the LN0 barrier below)
#pragma unroll
  for (int t = 0; t < 8; ++t)
    gload_lds16(WoT + offA[t], As[0] + uOff[t]);

  // ---- LN0 prologue: thread owns row q=tid>>3, cols (tid&7)*64..+63 ----
  {
    const int q = tid >> 3, c0 = (tid & 7) * 64;
    const bf16* src = Orb + (size_t)(m0 + q) * DV + c0;
    float x[64];
    float s = 0.f, s2 = 0.f;
#pragma unroll
    for (int j = 0; j < 8; ++j) {
      bf16x8 xv = *(const bf16x8*)(src + j * 8);
#pragma unroll
      for (int e = 0; e < 8; ++e) {
        float f = (float)xv[e];
        x[j * 8 + e] = f; s += f; s2 += f * f;
      }
    }
    s  += __shfl_xor(s, 1);  s  += __shfl_xor(s, 2);  s  += __shfl_xor(s, 4);
    s2 += __shfl_xor(s2, 1); s2 += __shfl_xor(s2, 2); s2 += __shfl_xor(s2, 4);
    float mu = s * (1.f / DV);
    float inv = rsqrtf(s2 * (1.f / DV) - mu * mu + 1e-5f);
#pragma unroll
    for (int j = 0; j < 8; ++j) {
      float4 ga = *(const float4*)(g0 + c0 + j * 8);
      float4 gb = *(const float4*)(g0 + c0 + j * 8 + 4);
      float4 ba = *(const float4*)(b0 + c0 + j * 8);
      float4 bb = *(const float4*)(b0 + c0 + j * 8 + 4);
      bf16x8 o;
      o[0] = (bf16)((x[j*8+0] - mu) * inv * ga.x + ba.x);
      o[1] = (bf16)((x[j*8+1] - mu) * inv * ga.y + ba.y);
      o[2] = (bf16)((x[j*8+2] - mu) * inv * ga.z + ba.z);
      o[3] = (bf16)((x[j*8+3] - mu) * inv * ga.w + ba.w);
      o[4] = (bf16)((x[j*8+4] - mu) * inv * gb.x + bb.x);
      o[5] = (bf16)((x[j*8+5] - mu) * inv * gb.y + bb.y);
      o[6] = (bf16)((x[j*8+6] - mu) * inv * gb.z + bb.z);
      o[7] = (bf16)((x[j*8+7] - mu) * inv * gb.w + bb.w);
      int g = (tid & 7) * 8 + j;
      int slot = q * 64 + (g ^ (q & 7));
      *(bf16x8*)(Bsm + (size_t)slot * 8) = o;
    }
  }

  f32x4 acc[8][2] = {};
  for (int it = 0; it < 16; ++it) {
    __syncthreads();                       // publishes Bsm (it=0) + As[cur]
    const int cur = it & 1;
    if (it + 1 < 16) {
#pragma unroll
      for (int t = 0; t < 8; ++t)
        gload_lds16(WoT + (size_t)(it + 1) * 32 + offA[t], As[cur ^ 1] + uOff[t]);
    }
    bf16x8 bfr[2];
#pragma unroll
    for (int nt = 0; nt < 2; ++nt) {
      int q = nt * 16 + cl;
      int slot = q * 64 + ((it * 4 + qd) ^ (q & 7));
      bfr[nt] = *(const bf16x8*)(Bsm + (size_t)slot * 8);
    }
#pragma unroll
    for (int mt = 0; mt < 8; ++mt) {
      int frow = (w * 8 + mt) * 16 + cl;
      int slot = frow * 4 + (qd ^ ((frow >> 1) & 3));
      bf16x8 af = *(const bf16x8*)(As[cur] + (size_t)slot * 8);
#pragma unroll
      for (int nt = 0; nt < 2; ++nt)
        acc[mt][nt] = __builtin_amdgcn_mfma_f32_16x16x32_bf16(
            af, bfr[nt], acc[mt][nt], 0, 0, 0);
    }
  }

  // ---- epilogue: Y = res + relu(acc + bo), then LN1 over full rows ----
  __syncthreads();                          // As now reusable as scratch
  float* red = (float*)As;                  // [32 q][4 w][2]
  float y[8][2][4];
  float sy[2], sy2[2];
#pragma unroll
  for (int nt = 0; nt < 2; ++nt) {
    sy[nt] = 0.f; sy2[nt] = 0.f;
    const int q = nt * 16 + cl;
#pragma unroll
    for (int mt = 0; mt < 8; ++mt) {
      const int f0 = (w * 8 + mt) * 16 + qd * 4;
      float4 bov = *(const float4*)(bo + f0);
      int g = f0 >> 3;
      int slot = q * 64 + (g ^ (q & 7));
      bf16x4 rv = *(const bf16x4*)(Bsm + (size_t)slot * 8 + (qd & 1) * 4);
      const float* bp = (const float*)&bov;
#pragma unroll
      for (int r = 0; r < 4; ++r) {
        float v = fmaxf(acc[mt][nt][r] + bp[r], 0.f) + (float)rv[r];
        y[mt][nt][r] = v;
        sy[nt] += v; sy2[nt] += v * v;
      }
    }
    sy[nt]  += __shfl_xor(sy[nt], 16);  sy[nt]  += __shfl_xor(sy[nt], 32);
    sy2[nt] += __shfl_xor(sy2[nt], 16); sy2[nt] += __shfl_xor(sy2[nt], 32);
  }
  if (qd == 0) {
#pragma unroll
    for (int nt = 0; nt < 2; ++nt) {
      int q = nt * 16 + cl;
      red[(q * 4 + w) * 2 + 0] = sy[nt];
      red[(q * 4 + w) * 2 + 1] = sy2[nt];
    }
  }
  __syncthreads();
#pragma unroll
  for (int nt = 0; nt < 2; ++nt) {
    const int q = nt * 16 + cl;
    float s = 0.f, s2 = 0.f;
#pragma unroll
    for (int ww = 0; ww < 4; ++ww) {
      s  += red[(q * 4 + ww) * 2 + 0];
      s2 += red[(q * 4 + ww) * 2 + 1];
    }
    float mu1 = s * (1.f / DV);
    float inv1 = rsqrtf(s2 * (1.f / DV) - mu1 * mu1 + 1e-5f);
    size_t rowoff = (size_t)(m0 + q) * DV;
#pragma unroll
    for (int mt = 0; mt < 8; ++mt) {
      const int f0 = (w * 8 + mt) * 16 + qd * 4;
      float4 gv = *(const float4*)(g1 + f0);
      float4 bv = *(const float4*)(b1 + f0);
      float4 ov;
      ov.x = (y[mt][nt][0] - mu1) * inv1 * gv.x + bv.x;
      ov.y = (y[mt][nt][1] - mu1) * inv1 * gv.y + bv.y;
      ov.z = (y[mt][nt][2] - mu1) * inv1 * gv.z + bv.z;
      ov.w = (y[mt][nt][3] - mu1) * inv1 * gv.w + bv.w;
      *(float4*)(out + rowoff + f0) = ov;
    }
  }
}

extern "C" void kernel_launch(void* const* d_in, const int* in_sizes, int n_in,
                              void* d_out, int out_size, void* d_ws, size_t ws_size,
                              hipStream_t stream)
{
  const float* Q  = (const float*)d_in[0];
  const float* Kf = (const float*)d_in[1];
  const float* Wq = (const float*)d_in[2];
  const float* bq = (const float*)d_in[3];
  const float* Wk = (const float*)d_in[4];
  const float* bk = (const float*)d_in[5];
  const float* Wv = (const float*)d_in[6];
  const float* bv = (const float*)d_in[7];
  const float* Wo = (const float*)d_in[8];
  const float* bo = (const float*)d_in[9];
  const float* g0 = (const float*)d_in[10];
  const float* b0 = (const float*)d_in[11];
  const float* g1 = (const float*)d_in[12];
  const float* b1 = (const float*)d_in[13];
  float* out = (float*)d_out;

  const size_t MB = 1ull << 20;
  char* W = (char*)d_ws;
  bf16* Orb = (bf16*)(W + 0);                    // 8 MB
  bf16* Qp  = (bf16*)(W + 8 * MB);
  bf16* Kp  = (bf16*)(W + 16 * MB);
  bf16* VpT = (bf16*)(W + 24 * MB);              // [512][8192]
  bf16* WqT = (bf16*)(W + 32 * MB);
  bf16* WkT = (bf16*)(W + 32 * MB + 512 * 1024);
  bf16* WvT = (bf16*)(W + 33 * MB);
  bf16* WoT = (bf16*)(W + 33 * MB + 512 * 1024);

  dim3 blk(256);
  prep_w<<<dim3(64, 1, 4), blk, 0, stream>>>(Wq, Wk, Wv, Wo, WqT, WkT, WvT, WoT);
  gemm_proj<<<dim3(256, 1, 3), blk, 0, stream>>>(
      Q, Kf, WqT, WkT, WvT, bq, bk, bv, Qp, Kp, VpT);
  attn_mfma<<<dim3(NBATCH * NHEADS, SEQ / 128), blk, 0, stream>>>(Qp, Kp, VpT, Orb);
  gemm_fused<<<dim3(MROWS / 32), blk, 0, stream>>>(
      Orb, WoT, bo, g0, b0, g1, b1, out);
}